// Round 5
// baseline (339.008 us; speedup 1.0000x reference)
//
#include <hip/hip_runtime.h>
#include <stdint.h>

#define B_    4
#define N_    2048
#define D_    4096
#define E_    64
#define TOKENS (B_ * N_)        // 8192
#define KT    16                // K-tile staged in LDS
#define TM    128               // tokens per block tile
#define KS    16                // split-K factor
#define KCHUNK (D_ / KS)        // 256
#define NIT   (KCHUNK / KT)     // 16 staging iterations per block
#define PA    (TM + 4)          // As pitch 132 (16B-aligned, 2-way banks only)
#define PW    (E_ + 4)          // Ws pitch 68

typedef float vfloat4 __attribute__((ext_vector_type(4)));

// ---------------------------------------------------------------------------
// K1: split-K fp32 GEMM + fused d_out zero-fill.
// 256 threads, tile 128 tok x 64 exp, thread tile 8 tok x 4 exp (32 acc).
// Software-pipelined: next K-tile is prefetched into registers during the
// FMA phase, so global loads stay in flight across the barrier.
// Per kk: 3 ds_read_b128 / 32 FMAs (LDS no longer oversubscribed).
// ---------------------------------------------------------------------------
__global__ __launch_bounds__(256) void k_gemm_z(const float* __restrict__ A,
                                                const float* __restrict__ W,
                                                float* __restrict__ P,
                                                float* __restrict__ out,
                                                float* __restrict__ probsum,
                                                float* __restrict__ losses) {
    __shared__ float As[KT][PA];
    __shared__ float Ws[KT][PW];

    const int tid   = threadIdx.x;
    const int tok0  = blockIdx.x * TM;
    const int kc    = blockIdx.y;
    const int kbase = kc * KCHUNK;
    const int blin  = kc * gridDim.x + blockIdx.x;   // 0..1023

    // compute mapping: 16 token-groups x 16 expert-groups
    const int t0 = (tid & 15) * 8;
    const int e0 = (tid >> 4) * 4;

    // A staging: k=(tid&3)*4, tokens tid>>2 and +64  (LDS writes 2-way only)
    const int a_k = (tid & 3) * 4;
    const int a_t = tid >> 2;
    // W staging: row tid>>4, 4 experts
    const int w_k = tid >> 4;
    const int w_e = (tid & 15) * 4;

    // zero-fill: block covers float4 range [blin*10240, (blin+1)*10240)
    vfloat4* zbase = reinterpret_cast<vfloat4*>(out) + (size_t)blin * 10240 + tid;
    int zstep = 0;
    const vfloat4 z4 = {0.f, 0.f, 0.f, 0.f};

    if (blin == 0) {
        probsum[tid] = 0.f;              // 256 = B_*E_ entries
        if (tid < 2) losses[tid] = 0.f;
    }

    const float* gA = A + (size_t)tok0 * D_ + kbase;

    // prologue: prefetch tile 0 into registers
    float4 pa0 = *reinterpret_cast<const float4*>(gA + (size_t)a_t * D_ + a_k);
    float4 pa1 = *reinterpret_cast<const float4*>(gA + (size_t)(a_t + 64) * D_ + a_k);
    float4 pw  = *reinterpret_cast<const float4*>(W + (size_t)(kbase + w_k) * E_ + w_e);

    float acc[8][4] = {{0.f}};

    #pragma unroll 1
    for (int it = 0; it < NIT; ++it) {
        // commit prefetched tile to LDS
        As[a_k + 0][a_t]      = pa0.x;
        As[a_k + 1][a_t]      = pa0.y;
        As[a_k + 2][a_t]      = pa0.z;
        As[a_k + 3][a_t]      = pa0.w;
        As[a_k + 0][a_t + 64] = pa1.x;
        As[a_k + 1][a_t + 64] = pa1.y;
        As[a_k + 2][a_t + 64] = pa1.z;
        As[a_k + 3][a_t + 64] = pa1.w;
        *reinterpret_cast<float4*>(&Ws[w_k][w_e]) = pw;
        __syncthreads();

        // issue next tile's global loads (in flight during FMA below)
        if (it + 1 < NIT) {
            const int ko = (it + 1) * KT;
            pa0 = *reinterpret_cast<const float4*>(gA + (size_t)a_t * D_ + ko + a_k);
            pa1 = *reinterpret_cast<const float4*>(gA + (size_t)(a_t + 64) * D_ + ko + a_k);
            pw  = *reinterpret_cast<const float4*>(W + (size_t)(kbase + ko + w_k) * E_ + w_e);
        }

        // interleaved NT zero stores: 3/iter first 8 iters, 2 after -> 40
        {
            const int nz = (it < 8) ? 3 : 2;
            for (int j = 0; j < nz; ++j) {
                __builtin_nontemporal_store(z4, zbase + (size_t)zstep * 256);
                ++zstep;
            }
        }

        #pragma unroll
        for (int kk = 0; kk < KT; ++kk) {
            float a[8], b[4];
            *reinterpret_cast<float4*>(&a[0]) = *reinterpret_cast<const float4*>(&As[kk][t0]);
            *reinterpret_cast<float4*>(&a[4]) = *reinterpret_cast<const float4*>(&As[kk][t0 + 4]);
            *reinterpret_cast<float4*>(&b[0]) = *reinterpret_cast<const float4*>(&Ws[kk][e0]);
            #pragma unroll
            for (int i = 0; i < 8; ++i)
                #pragma unroll
                for (int j = 0; j < 4; ++j)
                    acc[i][j] += a[i] * b[j];
        }
        __syncthreads();
    }

    float* base = P + ((size_t)kc * TOKENS + tok0) * E_;
    #pragma unroll
    for (int i = 0; i < 8; ++i) {
        const float4 v = make_float4(acc[i][0], acc[i][1], acc[i][2], acc[i][3]);
        *reinterpret_cast<float4*>(&base[(size_t)(t0 + i) * E_ + e0]) = v;
    }
}

// ---------------------------------------------------------------------------
// K2: reduce split-K partials; per-token softmax stats (wave per token, lane =
// expert). Writes argmax idx, gate (=max prob), accumulates probsum[b][e] and
// the z-loss (atomic, pre-scaled).
// ---------------------------------------------------------------------------
__global__ __launch_bounds__(256) void k_softmax(const float* __restrict__ P,
                                                 int* __restrict__ idx,
                                                 float* __restrict__ gate,
                                                 float* __restrict__ probsum,
                                                 float* __restrict__ out_z) {
    const int tid  = threadIdx.x;
    const int wid  = tid >> 6;
    const int lane = tid & 63;
    const int tok  = blockIdx.x * 4 + wid;

    float l = 0.f;
    #pragma unroll
    for (int kc = 0; kc < KS; ++kc)
        l += P[((size_t)kc * TOKENS + tok) * E_ + lane];

    // wave argmax, first-index tie-break (matches numpy)
    float m = l; int mi = lane;
    #pragma unroll
    for (int off = 32; off > 0; off >>= 1) {
        const float om = __shfl_down(m, off);
        const int   oi = __shfl_down(mi, off);
        if (om > m || (om == m && oi < mi)) { m = om; mi = oi; }
    }
    m  = __shfl(m, 0);
    mi = __shfl(mi, 0);

    const float p = __expf(l - m);
    float s = p;
    #pragma unroll
    for (int off = 32; off > 0; off >>= 1) s += __shfl_down(s, off);
    s = __shfl(s, 0);

    __shared__ float pacc[4][E_];
    __shared__ float zv[4];
    pacc[wid][lane] = p / s;
    if (lane == 0) {
        const float lse = m + logf(s);
        zv[wid]   = lse * lse;
        idx[tok]  = mi;
        gate[tok] = 1.0f / s;                 // exp(m-m)/s = max prob
    }
    __syncthreads();

    if (tid < E_) {
        const float ps = pacc[0][tid] + pacc[1][tid] + pacc[2][tid] + pacc[3][tid];
        const int b = (blockIdx.x * 4) / N_;  // block never crosses batch
        atomicAdd(&probsum[b * E_ + tid], ps);
    }
    if (tid == 0)
        atomicAdd(out_z, (zv[0] + zv[1] + zv[2] + zv[3]) * (1.0f / (float)TOKENS));
}

// ---------------------------------------------------------------------------
// K3: ordered position-in-expert via wave ballot (matches reference cumsum),
// scatter into dispatch/combine + aux-loss fused. One wave per (b,e).
// ---------------------------------------------------------------------------
__global__ __launch_bounds__(64) void k_posloss(const int* __restrict__ idx,
                                                const float* __restrict__ gate,
                                                const float* __restrict__ probsum,
                                                float* __restrict__ out,
                                                float* __restrict__ out_aux,
                                                int C, size_t half) {
    const int b = blockIdx.x >> 6;
    const int e = blockIdx.x & 63;
    const int lane = threadIdx.x;
    const int*   ib = idx  + b * N_;
    const float* gb = gate + b * N_;
    float* ob = out + (size_t)b * N_ * E_ * C;   // dispatch base for batch b

    int running = 0;
    for (int step = 0; step < N_ / 64; ++step) {
        const int t = step * 64 + lane;
        const bool match = (ib[t] == e);
        const unsigned long long mask = __ballot(match);
        if (match) {
            const int p = running + __popcll(mask & ((1ull << lane) - 1ull));
            if (p < C) {
                const size_t off = (size_t)t * E_ * C + (size_t)e * C + p;
                ob[off] = 1.0f;            // dispatch
                ob[half + off] = gb[t];    // combine
            }
        }
        running += __popcll(mask);
    }
    if (lane == 0)   // aux = sum(count * probsum) * E^2/(B*E*N*N) = sum/262144
        atomicAdd(out_aux,
                  (float)running * probsum[b * E_ + e] * (1.0f / 262144.0f));
}

// ---------------------------------------------------------------------------
extern "C" void kernel_launch(void* const* d_in, const int* in_sizes, int n_in,
                              void* d_out, int out_size, void* d_ws, size_t ws_size,
                              hipStream_t stream) {
    const float* A = (const float*)d_in[0];
    const float* W = (const float*)d_in[1];
    float* out = (float*)d_out;

    const size_t half = ((size_t)out_size - 2) / 2;          // TOKENS*E*C
    const int C = (int)(half / ((size_t)TOKENS * E_));       // 40

    float* P = (float*)d_ws;
    size_t off = (size_t)KS * TOKENS * E_;
    int*   idx     = (int*)(P + off);   off += TOKENS;
    float* gate    = P + off;           off += TOKENS;
    float* probsum = P + off;           off += B_ * E_;

    float* out_aux = out + 2 * half;
    float* out_z   = out + 2 * half + 1;

    // k_gemm_z zeroes all of d_out: 2*half = 41,943,040 floats =
    // 1024 blocks * 10240 float4 exactly; block 0 zeroes probsum + losses.
    k_gemm_z<<<dim3(TOKENS / TM, KS), 256, 0, stream>>>(A, W, P, out, probsum,
                                                        out_aux);
    k_softmax<<<TOKENS / 4, 256, 0, stream>>>(P, idx, gate, probsum, out_z);
    k_posloss<<<B_ * E_, 64, 0, stream>>>(idx, gate, probsum, out, out_aux, C, half);
}